// Round 3
// baseline (2512.792 us; speedup 1.0000x reference)
//
#include <hip/hip_runtime.h>

#define HH 20

__device__ __forceinline__ float sigm(float x) { return 1.0f / (1.0f + __expf(-x)); }
__device__ __forceinline__ float tnh(float x)  { return 1.0f - 2.0f / (__expf(2.0f * x) + 1.0f); }

template <int CTRL>
__device__ __forceinline__ float qperm(float x) {
    return __int_as_float(__builtin_amdgcn_mov_dpp(__float_as_int(x), CTRL, 0xF, 0xF, false));
}

// ---- 20 named scalar weights per gate (never an array -> never scratch) ----
#define DECL20(P) float P##_0,P##_1,P##_2,P##_3,P##_4,P##_5,P##_6,P##_7,P##_8,P##_9, \
                        P##_10,P##_11,P##_12,P##_13,P##_14,P##_15,P##_16,P##_17,P##_18,P##_19;

#define UNPACK20(P, l0, l1, l2, l3, l4) \
    P##_0=(l0).x; P##_1=(l0).y; P##_2=(l0).z; P##_3=(l0).w; \
    P##_4=(l1).x; P##_5=(l1).y; P##_6=(l1).z; P##_7=(l1).w; \
    P##_8=(l2).x; P##_9=(l2).y; P##_10=(l2).z; P##_11=(l2).w; \
    P##_12=(l3).x; P##_13=(l3).y; P##_14=(l3).z; P##_15=(l3).w; \
    P##_16=(l4).x; P##_17=(l4).y; P##_18=(l4).z; P##_19=(l4).w;

// keep values live in VGPRs across the loop: volatile asm result can't be
// rematerialized or sunk (the loads otherwise get re-issued every iteration)
#define PIN10(P) asm volatile("" : "+v"(P##_0),"+v"(P##_1),"+v"(P##_2),"+v"(P##_3),"+v"(P##_4), \
                                   "+v"(P##_5),"+v"(P##_6),"+v"(P##_7),"+v"(P##_8),"+v"(P##_9));
#define PIN20(P) PIN10(P) \
    asm volatile("" : "+v"(P##_10),"+v"(P##_11),"+v"(P##_12),"+v"(P##_13),"+v"(P##_14), \
                      "+v"(P##_15),"+v"(P##_16),"+v"(P##_17),"+v"(P##_18),"+v"(P##_19));

#define DOT20S(A, P) \
    A = fmaf(P##_0,  q0.x, A); A = fmaf(P##_1,  q0.y, A); A = fmaf(P##_2,  q0.z, A); A = fmaf(P##_3,  q0.w, A); \
    A = fmaf(P##_4,  q1.x, A); A = fmaf(P##_5,  q1.y, A); A = fmaf(P##_6,  q1.z, A); A = fmaf(P##_7,  q1.w, A); \
    A = fmaf(P##_8,  q2.x, A); A = fmaf(P##_9,  q2.y, A); A = fmaf(P##_10, q2.z, A); A = fmaf(P##_11, q2.w, A); \
    A = fmaf(P##_12, q3.x, A); A = fmaf(P##_13, q3.y, A); A = fmaf(P##_14, q3.z, A); A = fmaf(P##_15, q3.w, A); \
    A = fmaf(P##_16, q4.x, A); A = fmaf(P##_17, q4.y, A); A = fmaf(P##_18, q4.z, A); A = fmaf(P##_19, q4.w, A);

__global__ __launch_bounds__(64, 1)
void lstm2_kernel(const float* __restrict__ x_in,
                  const float* __restrict__ Wih1,
                  const float* __restrict__ Whh1,
                  const float* __restrict__ bih1,
                  const float* __restrict__ bhh1,
                  const float* __restrict__ Wih2,
                  const float* __restrict__ Whh2,
                  const float* __restrict__ bih2,
                  const float* __restrict__ bhh2,
                  float* __restrict__ out,
                  int T, int F)
{
    const int tid = threadIdx.x;
    const int e   = tid >> 5;          // which chain of this wave (0/1)
    const int j   = tid & 31;          // lane within 32-lane group
    const int b   = blockIdx.x * 2 + e;

    // [parity][group][ h1: 0..19 | c1: 24..43 ] (48-float stride)
    __shared__ float sb[2][2][48];
    __shared__ float c2bc[2];

    for (int i = tid; i < 2 * 2 * 48; i += 64) ((float*)sb)[i] = 0.0f;
    if (tid < 2) c2bc[tid] = 0.0f;
    __builtin_amdgcn_wave_barrier();

    // ---- load per-lane weights, then unpack into named scalars ----
    const float4 *P0, *P1, *P2, *P3;
    if (j < HH) {
        P0 = (const float4*)(Whh1 + j * HH);
        P1 = (const float4*)(Whh1 + (HH + j) * HH);
        P2 = (const float4*)(Whh1 + (2 * HH + j) * HH);
        P3 = (const float4*)(Whh1 + (3 * HH + j) * HH);
    } else if (j < 24) {
        P0 = (const float4*)(Wih2 + (j - HH) * HH);
        P1 = P2 = P3 = (const float4*)Whh1;   // valid dummy rows
    } else {
        P0 = P1 = P2 = P3 = (const float4*)Whh1;
    }
    float4 l0, l1, l2, l3, l4;
    DECL20(u0) DECL20(u1) DECL20(u2) DECL20(u3)
    l0 = P0[0]; l1 = P0[1]; l2 = P0[2]; l3 = P0[3]; l4 = P0[4];
    UNPACK20(u0, l0, l1, l2, l3, l4)
    l0 = P1[0]; l1 = P1[1]; l2 = P1[2]; l3 = P1[3]; l4 = P1[4];
    UNPACK20(u1, l0, l1, l2, l3, l4)
    l0 = P2[0]; l1 = P2[1]; l2 = P2[2]; l3 = P2[3]; l4 = P2[4];
    UNPACK20(u2, l0, l1, l2, l3, l4)
    l0 = P3[0]; l1 = P3[1]; l2 = P3[2]; l3 = P3[3]; l4 = P3[4];
    UNPACK20(u3, l0, l1, l2, l3, l4)

    float wx0 = 0, wx1 = 0, wx2 = 0, wx3 = 0, bs0 = 0, bs1 = 0, bs2 = 0, bs3 = 0;
    if (j < HH) {
        wx0 = Wih1[j]; wx1 = Wih1[HH + j]; wx2 = Wih1[2 * HH + j]; wx3 = Wih1[3 * HH + j];
        bs0 = bih1[j] + bhh1[j];
        bs1 = bih1[HH + j] + bhh1[HH + j];
        bs2 = bih1[2 * HH + j] + bhh1[2 * HH + j];
        bs3 = bih1[3 * HH + j] + bhh1[3 * HH + j];
    } else if (j < 24) {
        int g = j - HH;
        wx0 = Whh2[g];                 // multiplies h2 (scalar, O=1)
        bs0 = bih2[g] + bhh2[g];
    }

    // pin everything loop-invariant into VGPRs
    PIN20(u0) PIN20(u1) PIN20(u2) PIN20(u3)
    asm volatile("" : "+v"(wx0),"+v"(wx1),"+v"(wx2),"+v"(wx3),
                      "+v"(bs0),"+v"(bs1),"+v"(bs2),"+v"(bs3));

    float cmy  = 0.0f;   // c1[j] (j<20) | c2 (lanes 20..23, replicated)
    float h2my = 0.0f;   // h2 (lanes 20..23, replicated)
    float actp = 0.0f;   // layer-2 own-gate activation from previous iter

    const long xbase = (long)b * T;
    const long obase = (long)b * (T + F);
    const int  roff  = (j < HH) ? 0 : 24;   // layer-1 reads h-block, layer-2 reads c-block

    // 3-deep x prefetch pipeline
    float xr = x_in[xbase];
    float x1 = x_in[xbase + (T > 1 ? 1 : 0)];
    float x2 = x_in[xbase + (T > 2 ? 2 : 0)];

    // ================= main scan; layer-2 combine runs 2 steps behind =================
    for (int t = 0; t < T; ++t) {
        const float* rb   = &sb[t & 1][e][0];
        float*       wbuf = &sb[(t & 1) ^ 1][e][0];

        // issue the h/c broadcast reads first (latency overlaps the combine below)
        const float4* vb = (const float4*)(rb + roff);
        float4 q0 = vb[0], q1 = vb[1], q2 = vb[2], q3 = vb[3], q4 = vb[4];

        int tn = t + 3; tn = (tn < T) ? tn : (T - 1);
        const float xf = x_in[xbase + tn];

        // layer-2 combine for step s = t-2 (uses actp from previous iteration)
        if (j >= HH) {
            float ai = qperm<0x00>(actp), af = qperm<0x55>(actp);
            float ag = qperm<0xAA>(actp), ao = qperm<0xFF>(actp);
            if (t >= 2) {
                float c2n = af * cmy + ai * ag;
                h2my = ao * tnh(c2n);
                cmy  = c2n;
                if (j == HH) out[obase + t - 2] = c2n;
            }
        }

        const float xin = (j < HH) ? xr : h2my;
        float a0 = fmaf(wx0, xin, bs0);
        float a1 = fmaf(wx1, xr, bs1);
        float a2 = fmaf(wx2, xr, bs2);
        float a3 = fmaf(wx3, xr, bs3);
        DOT20S(a0, u0)
        DOT20S(a1, u1)
        DOT20S(a2, u2)
        DOT20S(a3, u3)

        if (j < HH) {
            float ig = sigm(a0), fg = sigm(a1), gg = tnh(a2), og = sigm(a3);
            float cn = fg * cmy + ig * gg;
            cmy = cn;
            wbuf[24 + j] = cn;           // c first: layer-2 reads this next step
            float hn = og * tnh(cn);
            wbuf[j]      = hn;
        } else {
            actp = (j == HH + 2) ? tnh(a0) : sigm(a0);   // lane 22 is gate 'g' (tanh)
        }
        __builtin_amdgcn_wave_barrier();
        xr = x1; x1 = x2; x2 = xf;
    }

    // ================= drain =================
    // combine s = T-2
    if (j >= HH) {
        float ai = qperm<0x00>(actp), af = qperm<0x55>(actp);
        float ag = qperm<0xAA>(actp), ao = qperm<0xFF>(actp);
        float c2n = af * cmy + ai * ag;
        h2my = ao * tnh(c2n);
        cmy  = c2n;
        if (j == HH) out[obase + T - 2] = c2n;
    }
    // full layer-2 step s = T-1 (c1(T-1) sits in sb[T&1])
    if (j >= HH) {
        const float4* vb = (const float4*)(&sb[T & 1][e][24]);
        float4 q0 = vb[0], q1 = vb[1], q2 = vb[2], q3 = vb[3], q4 = vb[4];
        float a0 = fmaf(wx0, h2my, bs0);
        DOT20S(a0, u0)
        float actn = (j == HH + 2) ? tnh(a0) : sigm(a0);
        float ai = qperm<0x00>(actn), af = qperm<0x55>(actn);
        float ag = qperm<0xAA>(actn), ao = qperm<0xFF>(actn);
        float c2n = af * cmy + ai * ag;
        h2my = ao * tnh(c2n);
        cmy  = c2n;
        if (j == HH) { out[obase + T - 1] = c2n; c2bc[e] = c2n; }
    }
    __builtin_amdgcn_wave_barrier();

    // ================= future phase (serial, F=16) =================
    int p = T & 1;
    for (int i = 0; i < F; ++i) {
        const float xb = c2bc[e];
        const float* rb   = &sb[p][e][0];
        float*       wbuf = &sb[p ^ 1][e][0];

        if (j < HH) {
            const float4* vb = (const float4*)rb;
            float4 q0 = vb[0], q1 = vb[1], q2 = vb[2], q3 = vb[3], q4 = vb[4];
            float a0 = fmaf(wx0, xb, bs0);
            float a1 = fmaf(wx1, xb, bs1);
            float a2 = fmaf(wx2, xb, bs2);
            float a3 = fmaf(wx3, xb, bs3);
            DOT20S(a0, u0)
            DOT20S(a1, u1)
            DOT20S(a2, u2)
            DOT20S(a3, u3)
            float ig = sigm(a0), fg = sigm(a1), gg = tnh(a2), og = sigm(a3);
            float cn = fg * cmy + ig * gg;
            cmy = cn;
            wbuf[24 + j] = cn;
            float hn = og * tnh(cn);
            wbuf[j]      = hn;
        }
        __builtin_amdgcn_wave_barrier();
        if (j >= HH) {
            const float4* vb = (const float4*)(wbuf + 24);   // c1 of THIS step
            float4 q0 = vb[0], q1 = vb[1], q2 = vb[2], q3 = vb[3], q4 = vb[4];
            float a0 = fmaf(wx0, h2my, bs0);
            DOT20S(a0, u0)
            float actn = (j == HH + 2) ? tnh(a0) : sigm(a0);
            float ai = qperm<0x00>(actn), af = qperm<0x55>(actn);
            float ag = qperm<0xAA>(actn), ao = qperm<0xFF>(actn);
            float c2n = af * cmy + ai * ag;
            h2my = ao * tnh(c2n);
            cmy  = c2n;
            if (j == HH) { out[obase + T + i] = c2n; c2bc[e] = c2n; }
        }
        __builtin_amdgcn_wave_barrier();
        p ^= 1;
    }
}

extern "C" void kernel_launch(void* const* d_in, const int* in_sizes, int n_in,
                              void* d_out, int out_size, void* d_ws, size_t ws_size,
                              hipStream_t stream) {
    const float* x    = (const float*)d_in[0];
    const float* Wih1 = (const float*)d_in[1];
    const float* Whh1 = (const float*)d_in[2];
    const float* bih1 = (const float*)d_in[3];
    const float* bhh1 = (const float*)d_in[4];
    const float* Wih2 = (const float*)d_in[5];
    const float* Whh2 = (const float*)d_in[6];
    const float* bih2 = (const float*)d_in[7];
    const float* bhh2 = (const float*)d_in[8];
    float* out = (float*)d_out;

    const int B = 1024;
    const int T = in_sizes[0] / B;        // 4096
    const int F = out_size / B - T;       // 16

    hipLaunchKernelGGL(lstm2_kernel, dim3(B / 2), dim3(64), 0, stream,
                       x, Wih1, Whh1, bih1, bhh1, Wih2, Whh2, bih2, bhh2, out, T, F);
}

// Round 4
// 1644.537 us; speedup vs baseline: 1.5280x; 1.5280x over previous
//
#include <hip/hip_runtime.h>

#define REP20(M) M(0) M(1) M(2) M(3) M(4) M(5) M(6) M(7) M(8) M(9) \
                 M(10) M(11) M(12) M(13) M(14) M(15) M(16) M(17) M(18) M(19)

__device__ __forceinline__ float rl(float x, int l) {
    return __int_as_float(__builtin_amdgcn_readlane(__float_as_int(x), l));
}
template <int C>
__device__ __forceinline__ float qperm(float x) {
    return __int_as_float(__builtin_amdgcn_mov_dpp(__float_as_int(x), C, 0xF, 0xF, false));
}
__device__ __forceinline__ float rcp_(float x) { return __builtin_amdgcn_rcpf(x); }

// act(a; m): m=1 -> sigmoid(a), m=2 -> tanh(a) = 2*sigm(2a)-1
__device__ __forceinline__ float actf(float a, float m) {
    float r = rcp_(1.0f + __expf(-m * a));
    return fmaf(m, r - 1.0f, 1.0f);
}
__device__ __forceinline__ float sigmf(float a) { return rcp_(1.0f + __expf(-a)); }
__device__ __forceinline__ float tanh_(float a) {
    return fmaf(2.0f, rcp_(1.0f + __expf(-2.0f * a)) - 1.0f, 1.0f);
}

// 20-term dot, 4 independent chains; P=weight prefix (VGPRs), S=state prefix (SGPRs)
#define DOT20(P, S, R)                                                \
    {                                                                 \
        float z0 = P##0 * S##0, z1 = P##1 * S##1;                     \
        float z2 = P##2 * S##2, z3 = P##3 * S##3;                     \
        z0 = fmaf(P##4,  S##4,  z0); z1 = fmaf(P##5,  S##5,  z1);     \
        z2 = fmaf(P##6,  S##6,  z2); z3 = fmaf(P##7,  S##7,  z3);     \
        z0 = fmaf(P##8,  S##8,  z0); z1 = fmaf(P##9,  S##9,  z1);     \
        z2 = fmaf(P##10, S##10, z2); z3 = fmaf(P##11, S##11, z3);     \
        z0 = fmaf(P##12, S##12, z0); z1 = fmaf(P##13, S##13, z1);     \
        z2 = fmaf(P##14, S##14, z2); z3 = fmaf(P##15, S##15, z3);     \
        z0 = fmaf(P##16, S##16, z0); z1 = fmaf(P##17, S##17, z1);     \
        z2 = fmaf(P##18, S##18, z2); z3 = fmaf(P##19, S##19, z3);     \
        R += (z0 + z1) + (z2 + z3);                                   \
    }

#define RLH(k) sh##k = rl(hn, k);
#define RLC(k) sc##k = rl(cn, k);

__global__ __launch_bounds__(64, 1)
void lstm2_kernel(const float* __restrict__ x_in,
                  const float* __restrict__ Wih1,
                  const float* __restrict__ Whh1,
                  const float* __restrict__ bih1,
                  const float* __restrict__ bhh1,
                  const float* __restrict__ Wih2,
                  const float* __restrict__ Whh2,
                  const float* __restrict__ bih2,
                  const float* __restrict__ bhh2,
                  float* __restrict__ out,
                  int T, int F)
{
    const int lane = threadIdx.x;          // block = 64 = 1 wave = 1 batch chain
    const int b    = blockIdx.x;
    const bool isL2 = (lane >= 20 && lane < 24);
    const bool isU  = (lane < 20) || (lane >= 32 && lane < 52);

    // row assignment: lane j<20 -> rows (j, 20+j) = gates (i,f) of unit j
    //                 lane 32+j -> rows (40+j, 60+j) = gates (g,o)
    int rA = 0, rB = 0;
    if (lane < 20)                    { rA = lane;           rB = lane + 20; }
    else if (lane >= 32 && lane < 52) { rA = lane - 32 + 40; rB = lane - 32 + 60; }

    const float* WAp = isL2 ? (Wih2 + (lane - 20) * 20) : (Whh1 + rA * 20);
    const float* WBp = Whh1 + rB * 20;

#define LDW(k) float wA##k = WAp[k]; float wB##k = WBp[k];
    REP20(LDW)
#undef LDW

    float wxA = 0, wxB = 0, bsA = 0, bsB = 0;
    if (isU) {
        wxA = Wih1[rA]; wxB = Wih1[rB];
        bsA = bih1[rA] + bhh1[rA];
        bsB = bih1[rB] + bhh1[rB];
    } else if (isL2) {
        int g = lane - 20;
        wxA = Whh2[g];                  // multiplies h2 (O=1)
        bsA = bih2[g] + bhh2[g];
    }
    const bool tanhA = (lane >= 32 && lane < 52) || (lane == 22);  // g-gate rows + layer-2 'g'
    const float mA = tanhA ? 2.0f : 1.0f;

    // broadcast state in SGPRs (uniform values via readlane)
#define DSH(k) float sh##k = 0.0f; float sc##k = 0.0f;
    REP20(DSH)
#undef DSH

    float c1my = 0.0f;                 // unit lanes: c1[j] (both halves track it)
    float c2my = 0.0f, h2my = 0.0f;    // layer-2 state (meaningful on lanes 20..23)

    const long xbase = (long)b * T;
    const long obase = (long)b * (T + F);

    float xr = x_in[xbase];
    float x1 = x_in[xbase + (T > 1 ? 1 : 0)];
    float x2 = x_in[xbase + (T > 2 ? 2 : 0)];

    // ============== main scan: layer-2 dot uses sc = c1(t-1), combine in-iter ==============
    for (int t = 0; t < T; ++t) {
        const float xinA = isL2 ? h2my : xr;
        float aA = fmaf(wxA, xinA, bsA);
        float aB = fmaf(wxB, xr,   bsB);
        float a2 = fmaf(wxA, xinA, bsA);
        DOT20(wA, sh, aA)
        DOT20(wB, sh, aB)
        DOT20(wA, sc, a2)              // layer-2 rows over c1(t-1); garbage on unit lanes

        float actA = actf(aA, mA);     // i (lanes<32) / g [tanh] (lanes>=32)
        float actB = sigmf(aB);        // f / o
        float act2 = actf(a2, mA);     // layer-2 own gate (lane22 tanh)

        float swA = __shfl_xor(actA, 32);
        float swB = __shfl_xor(actB, 32);
        const bool lo = (lane < 32);
        float gi = lo ? actA : swA;
        float gf = lo ? actB : swB;
        float gg = lo ? swA : actA;
        float go = lo ? swB : actB;

        float cn = fmaf(gf, c1my, gi * gg);
        float hn = go * tanh_(cn);
        c1my = cn;

        REP20(RLH)                     // sh <- h1(t)
        REP20(RLC)                     // sc <- c1(t)

        if (t > 0) {                   // layer-2 step t-1 combine (wave-uniform branch)
            float i2 = qperm<0x00>(act2);
            float f2 = qperm<0x55>(act2);
            float g2 = qperm<0xAA>(act2);
            float o2 = qperm<0xFF>(act2);
            float c2n = fmaf(f2, c2my, i2 * g2);
            h2my = o2 * tanh_(c2n);
            c2my = c2n;
            if (lane == 20) out[obase + t - 1] = c2n;
        }

        int tn = t + 3; tn = (tn < T) ? tn : (T - 1);
        xr = x1; x1 = x2; x2 = x_in[xbase + tn];
    }

    // ============== drain: layer-2 step T-1 (sc = c1(T-1)) ==============
    {
        float a2 = fmaf(wxA, h2my, bsA);
        DOT20(wA, sc, a2)
        float act2 = actf(a2, mA);
        float i2 = qperm<0x00>(act2);
        float f2 = qperm<0x55>(act2);
        float g2 = qperm<0xAA>(act2);
        float o2 = qperm<0xFF>(act2);
        float c2n = fmaf(f2, c2my, i2 * g2);
        h2my = o2 * tanh_(c2n);
        c2my = c2n;
        if (lane == 20) out[obase + T - 1] = c2n;
    }
    float xF = rl(c2my, 20);           // uniform: feedback input for future phase

    // ============== future phase: layer1 then layer2 within each step ==============
    for (int i = 0; i < F; ++i) {
        const float xinA = isL2 ? h2my : xF;
        float aA = fmaf(wxA, xinA, bsA);
        float aB = fmaf(wxB, xF,   bsB);
        DOT20(wA, sh, aA)
        DOT20(wB, sh, aB)
        float actA = actf(aA, mA);
        float actB = sigmf(aB);
        float swA = __shfl_xor(actA, 32);
        float swB = __shfl_xor(actB, 32);
        const bool lo = (lane < 32);
        float gi = lo ? actA : swA;
        float gf = lo ? actB : swB;
        float gg = lo ? swA : actA;
        float go = lo ? swB : actB;
        float cn = fmaf(gf, c1my, gi * gg);
        float hn = go * tanh_(cn);
        c1my = cn;
        REP20(RLH)
        REP20(RLC)                     // sc <- c1 of THIS step
        float a2 = fmaf(wxA, h2my, bsA);
        DOT20(wA, sc, a2)
        float act2 = actf(a2, mA);
        float i2 = qperm<0x00>(act2);
        float f2 = qperm<0x55>(act2);
        float g2 = qperm<0xAA>(act2);
        float o2 = qperm<0xFF>(act2);
        float c2n = fmaf(f2, c2my, i2 * g2);
        h2my = o2 * tanh_(c2n);
        c2my = c2n;
        if (lane == 20) out[obase + T + i] = c2n;
        xF = rl(c2my, 20);
    }
}

extern "C" void kernel_launch(void* const* d_in, const int* in_sizes, int n_in,
                              void* d_out, int out_size, void* d_ws, size_t ws_size,
                              hipStream_t stream) {
    const float* x    = (const float*)d_in[0];
    const float* Wih1 = (const float*)d_in[1];
    const float* Whh1 = (const float*)d_in[2];
    const float* bih1 = (const float*)d_in[3];
    const float* bhh1 = (const float*)d_in[4];
    const float* Wih2 = (const float*)d_in[5];
    const float* Whh2 = (const float*)d_in[6];
    const float* bih2 = (const float*)d_in[7];
    const float* bhh2 = (const float*)d_in[8];
    float* out = (float*)d_out;

    const int B = 1024;
    const int T = in_sizes[0] / B;        // 4096
    const int F = out_size / B - T;       // 16

    hipLaunchKernelGGL(lstm2_kernel, dim3(B), dim3(64), 0, stream,
                       x, Wih1, Whh1, bih1, bhh1, Wih2, Whh2, bih2, bhh2, out, T, F);
}

// Round 5
// 1373.665 us; speedup vs baseline: 1.8293x; 1.1972x over previous
//
#include <hip/hip_runtime.h>

typedef float v2f __attribute__((ext_vector_type(2)));

__device__ __forceinline__ float rl20(float x) {
    return __int_as_float(__builtin_amdgcn_readlane(__float_as_int(x), 20));
}
template <int C>
__device__ __forceinline__ float qperm(float x) {
    return __int_as_float(__builtin_amdgcn_mov_dpp(__float_as_int(x), C, 0xF, 0xF, false));
}
__device__ __forceinline__ float rcp_(float x) { return __builtin_amdgcn_rcpf(x); }
__device__ __forceinline__ float sigmf(float a) { return rcp_(1.0f + __expf(-a)); }
__device__ __forceinline__ float tanh_(float a) {
    return fmaf(2.0f, rcp_(1.0f + __expf(-2.0f * a)) - 1.0f, 1.0f);
}
// m=1 -> sigmoid, m=2 -> tanh
__device__ __forceinline__ float actf(float a, float m) {
    float r = rcp_(1.0f + __expf(-m * a));
    return fmaf(m, r - 1.0f, 1.0f);
}

#define FMA2(a, b, c) __builtin_elementwise_fma(a, b, c)

// R += dot over 10 v2f pairs (packed fp32 FMA), state s0..s9 in scope
#define DOTP(P, R) { \
    v2f z0 = P##0 * s0; v2f z1 = P##1 * s1; \
    z0 = FMA2(P##2, s2, z0); z1 = FMA2(P##3, s3, z1); \
    z0 = FMA2(P##4, s4, z0); z1 = FMA2(P##5, s5, z1); \
    z0 = FMA2(P##6, s6, z0); z1 = FMA2(P##7, s7, z1); \
    z0 = FMA2(P##8, s8, z0); z1 = FMA2(P##9, s9, z1); \
    z0 = z0 + z1; R += z0.x + z0.y; }

// declare s0..s9 from 5 float4 LDS reads at BASE (float4-aligned)
#define LOADQ(BASE) \
    float4 A4 = (BASE)[0], B4 = (BASE)[1], C4 = (BASE)[2], D4 = (BASE)[3], E4 = (BASE)[4]; \
    v2f s0 = {A4.x, A4.y}, s1 = {A4.z, A4.w}, s2 = {B4.x, B4.y}, s3 = {B4.z, B4.w}, \
        s4 = {C4.x, C4.y}, s5 = {C4.z, C4.w}, s6 = {D4.x, D4.y}, s7 = {D4.z, D4.w}, \
        s8 = {E4.x, E4.y}, s9 = {E4.z, E4.w};

__global__ __launch_bounds__(64, 1)
void lstm2_kernel(const float* __restrict__ x_in,
                  const float* __restrict__ Wih1,
                  const float* __restrict__ Whh1,
                  const float* __restrict__ bih1,
                  const float* __restrict__ bhh1,
                  const float* __restrict__ Wih2,
                  const float* __restrict__ Whh2,
                  const float* __restrict__ bih2,
                  const float* __restrict__ bhh2,
                  float* __restrict__ out,
                  int T, int F)
{
    const int  lane = threadIdx.x;       // 1 wave = 1 batch chain
    const int  b    = blockIdx.x;
    const int  j2   = lane & 31;
    const bool hi   = lane >= 32;
    const bool isL2 = (lane >= 20 && lane < 24);

    // [ h1: 0..19 | c1: 24..43 ]
    __shared__ float sb[48];
    if (lane < 48) sb[lane] = 0.0f;
    __builtin_amdgcn_wave_barrier();

    // lane j<20: rows (j, 20+j) = (i,f); lane 32+j: rows (40+j, 60+j) = (g,o)
    const int uj = (j2 < 20) ? j2 : 19;              // clamp (idle lanes)
    const int rA = uj + (hi ? 40 : 0);
    const int rB = uj + (hi ? 60 : 20);
    const int g4 = isL2 ? (lane - 20) : 0;

    const float* WArow = isL2 ? (Wih2 + g4 * 20) : (Whh1 + rA * 20);
    const float* WBrow = Whh1 + rB * 20;

    const float4* wap = (const float4*)WArow;
    const float4* wbp = (const float4*)WBrow;
    float4 La0 = wap[0], La1 = wap[1], La2 = wap[2], La3 = wap[3], La4 = wap[4];
    float4 Lb0 = wbp[0], Lb1 = wbp[1], Lb2 = wbp[2], Lb3 = wbp[3], Lb4 = wbp[4];
    v2f wa0 = {La0.x,La0.y}, wa1 = {La0.z,La0.w}, wa2 = {La1.x,La1.y}, wa3 = {La1.z,La1.w},
        wa4 = {La2.x,La2.y}, wa5 = {La2.z,La2.w}, wa6 = {La3.x,La3.y}, wa7 = {La3.z,La3.w},
        wa8 = {La4.x,La4.y}, wa9 = {La4.z,La4.w};
    v2f wb0 = {Lb0.x,Lb0.y}, wb1 = {Lb0.z,Lb0.w}, wb2 = {Lb1.x,Lb1.y}, wb3 = {Lb1.z,Lb1.w},
        wb4 = {Lb2.x,Lb2.y}, wb5 = {Lb2.z,Lb2.w}, wb6 = {Lb3.x,Lb3.y}, wb7 = {Lb3.z,Lb3.w},
        wb8 = {Lb4.x,Lb4.y}, wb9 = {Lb4.z,Lb4.w};

    float wxA, wxB, bsA, bsB;
    {
        float u_wxA = Wih1[rA], u_wxB = Wih1[rB];
        float u_bsA = bih1[rA] + bhh1[rA];
        float u_bsB = bih1[rB] + bhh1[rB];
        float l_wxA = Whh2[g4];                     // multiplies h2 (O=1)
        float l_bsA = bih2[g4] + bhh2[g4];
        wxA = isL2 ? l_wxA : u_wxA;
        bsA = isL2 ? l_bsA : u_bsA;
        wxB = u_wxB;  bsB = u_bsB;
    }
    const bool  tA = (hi && j2 < 20) || (lane == 22);   // tanh rows: g-gates + L2 'g'
    const float mA = tA ? 2.0f : 1.0f;

    const float4* sp  = (const float4*)(sb + (isL2 ? 24 : 0));
    const float4* spc = (const float4*)(sb + 24);

    float c1my = 0.0f, c2my = 0.0f, h2my = 0.0f;

    const float* xp = x_in + (long)b * T;
    float*       op = out  + (long)b * (T + F);

    float xr = xp[0];
    float x1 = xp[T > 1 ? 1 : 0];
    float x2 = xp[T > 2 ? 2 : 0];

    // ================= main scan =================
    for (int t = 0; t < T; ++t) {
        LOADQ(sp)                                   // h1(t-1) | c1(t-1) per roff
        int tn = t + 3; tn = (tn < T) ? tn : (T - 1);
        const float xf = xp[tn];

        const float xinA = isL2 ? h2my : xr;
        float aA = fmaf(wxA, xinA, bsA);
        float aB = fmaf(wxB, xr,   bsB);
        DOTP(wa, aA)
        DOTP(wb, aB)

        float actA = actf(aA, mA);                  // i / g(tanh) / L2-gate
        float actB = sigmf(aB);                     // f / o
        float swA = __shfl_xor(actA, 32);
        float swB = __shfl_xor(actB, 32);
        float gi = hi ? swA : actA;
        float gf = hi ? swB : actB;
        float gg = hi ? actA : swA;
        float go = hi ? actB : swB;

        float cn = fmaf(gf, c1my, gi * gg);
        c1my = cn;
        float hn = go * tanh_(cn);
        if (!hi && j2 < 20) { sb[24 + j2] = cn; sb[j2] = hn; }

        // layer-2 combine for step t-1 (actA on lanes 20-23 holds its gates)
        float i2  = qperm<0x00>(actA), f2 = qperm<0x55>(actA);
        float g2v = qperm<0xAA>(actA), o2 = qperm<0xFF>(actA);
        if (t > 0) {
            float c2n = fmaf(f2, c2my, i2 * g2v);
            h2my = o2 * tanh_(c2n);
            c2my = c2n;
            if (lane == 20) op[t - 1] = c2n;
        }
        asm volatile("" ::: "memory");
        __builtin_amdgcn_wave_barrier();
        xr = x1; x1 = x2; x2 = xf;
    }

    // ================= drain: layer-2 step T-1 =================
    {
        LOADQ(spc)                                  // c1(T-1)
        float a2 = fmaf(wxA, h2my, bsA);
        DOTP(wa, a2)
        float act2 = actf(a2, mA);
        float i2  = qperm<0x00>(act2), f2 = qperm<0x55>(act2);
        float g2v = qperm<0xAA>(act2), o2 = qperm<0xFF>(act2);
        float c2n = fmaf(f2, c2my, i2 * g2v);
        h2my = o2 * tanh_(c2n);
        c2my = c2n;
        if (lane == 20) op[T - 1] = c2n;
    }
    float xF = rl20(c2my);

    // ================= future phase (F steps) =================
    const float4* spH = (const float4*)sb;
    for (int i = 0; i < F; ++i) {
        {   // layer 1 over h1(prev), input xF
            LOADQ(spH)
            float aA = fmaf(wxA, xF, bsA);
            float aB = fmaf(wxB, xF, bsB);
            DOTP(wa, aA)
            DOTP(wb, aB)
            float actA = actf(aA, mA);
            float actB = sigmf(aB);
            float swA = __shfl_xor(actA, 32);
            float swB = __shfl_xor(actB, 32);
            float gi = hi ? swA : actA;
            float gf = hi ? swB : actB;
            float gg = hi ? actA : swA;
            float go = hi ? actB : swB;
            float cn = fmaf(gf, c1my, gi * gg);
            c1my = cn;
            float hn = go * tanh_(cn);
            if (!hi && j2 < 20) { sb[24 + j2] = cn; sb[j2] = hn; }
        }
        asm volatile("" ::: "memory");
        __builtin_amdgcn_wave_barrier();
        {   // layer 2 over c1(THIS step)
            LOADQ(spc)
            float a2 = fmaf(wxA, h2my, bsA);
            DOTP(wa, a2)
            float act2 = actf(a2, mA);
            float i2  = qperm<0x00>(act2), f2 = qperm<0x55>(act2);
            float g2v = qperm<0xAA>(act2), o2 = qperm<0xFF>(act2);
            float c2n = fmaf(f2, c2my, i2 * g2v);
            h2my = o2 * tanh_(c2n);
            c2my = c2n;
            if (lane == 20) op[T + i] = c2n;
        }
        xF = rl20(c2my);
        asm volatile("" ::: "memory");
        __builtin_amdgcn_wave_barrier();
    }
}

extern "C" void kernel_launch(void* const* d_in, const int* in_sizes, int n_in,
                              void* d_out, int out_size, void* d_ws, size_t ws_size,
                              hipStream_t stream) {
    const float* x    = (const float*)d_in[0];
    const float* Wih1 = (const float*)d_in[1];
    const float* Whh1 = (const float*)d_in[2];
    const float* bih1 = (const float*)d_in[3];
    const float* bhh1 = (const float*)d_in[4];
    const float* Wih2 = (const float*)d_in[5];
    const float* Whh2 = (const float*)d_in[6];
    const float* bih2 = (const float*)d_in[7];
    const float* bhh2 = (const float*)d_in[8];
    float* out = (float*)d_out;

    const int B = 1024;
    const int T = in_sizes[0] / B;        // 4096
    const int F = out_size / B - T;       // 16

    hipLaunchKernelGGL(lstm2_kernel, dim3(B), dim3(64), 0, stream,
                       x, Wih1, Whh1, bih1, bhh1, Wih2, Whh2, bih2, bhh2, out, T, F);
}